// Round 1
// baseline (239.317 us; speedup 1.0000x reference)
//
#include <hip/hip_runtime.h>
#include <hip/hip_bf16.h>

// Problem constants
#define HW16 16
#define PIX 256        // 16*16
#define G 128
#define CROP 14
#define HW2 196        // 14*14
#define B 128
#define C 512
#define NC 384         // 3*G  (K of GEMM)
#define NO 768         // output channels (N of GEMM)
#define M_TOTAL (B * HW2)   // 25088

typedef __bf16 bf16x8 __attribute__((ext_vector_type(8)));
typedef float  f32x4  __attribute__((ext_vector_type(4)));

// ---------------- Kernel 1: W (fp32, [768][384]) -> bf16 ----------------
__global__ void wconv_kernel(const float* __restrict__ W, __bf16* __restrict__ Wb) {
    int tid = blockIdx.x * blockDim.x + threadIdx.x;   // < 768*384 = 294912
    Wb[tid] = (__bf16)W[tid];
}

// ---------------- Kernel 2: gather -> feats[b][hw][c] bf16 ----------------
// feats[b, hw=i*14+j, c=t*128+g] = x_t[b, idx[t*128+g, p], p],
//   p = (offh[t*128+g]+i)*16 + (offw[t*128+g]+j)
__global__ void gather_kernel(const float* __restrict__ x1,
                              const float* __restrict__ x3,
                              const float* __restrict__ x5,
                              const int* __restrict__ idx,
                              const int* __restrict__ offh,
                              const int* __restrict__ offw,
                              __bf16* __restrict__ feats) {
    unsigned tid = blockIdx.x * blockDim.x + threadIdx.x;  // < 128*196*384
    unsigned c    = tid % NC;            // fastest: coalesced writes
    unsigned rest = tid / NC;
    unsigned hw   = rest % HW2;
    unsigned b    = rest / HW2;
    unsigned t = c >> 7;                 // c / 128
    unsigned i = hw / CROP;
    unsigned j = hw - i * CROP;
    unsigned h = (unsigned)offh[c] + i;  // c == t*128+g
    unsigned w = (unsigned)offw[c] + j;
    unsigned p = h * HW16 + w;
    unsigned ch = (unsigned)idx[c * PIX + p];
    const float* x = (t == 0) ? x1 : (t == 1) ? x3 : x5;
    float v = x[(b * C + ch) * PIX + p];
    feats[tid] = (__bf16)v;
}

// ---------------- Kernel 3: GEMM  out[b,o,hw] = sum_c W[o,c]*feats[b,hw,c] ----
// D-tile: rows = o (A-operand = W), cols = m=(b,hw) (B-operand = feats)
// Block: 256 threads = 4 waves (2x2), block tile O=64 x M=64, wave tile 32x32.
__global__ __launch_bounds__(256) void gemm_kernel(const __bf16* __restrict__ feats,
                                                   const __bf16* __restrict__ Wb,
                                                   float* __restrict__ out) {
    const int m_base = blockIdx.x * 64;
    const int o_base = blockIdx.y * 64;
    const int wave = threadIdx.x >> 6;
    const int lane = threadIdx.x & 63;
    const int wo = wave >> 1, wm = wave & 1;
    const int l15 = lane & 15;
    const int kl  = (lane >> 4) * 8;     // k-offset of this lane's 8 bf16

    const __bf16* Wr0 = Wb    + (o_base + wo * 32 + l15) * NC + kl;       // o_sub=0
    const __bf16* Wr1 = Wr0 + 16 * NC;                                    // o_sub=1
    const __bf16* Fr0 = feats + (unsigned)(m_base + wm * 32 + l15) * NC + kl;
    const __bf16* Fr1 = Fr0 + 16 * NC;

    f32x4 acc[2][2] = {};
#pragma unroll
    for (int k0 = 0; k0 < NC; k0 += 32) {
        bf16x8 a0 = *reinterpret_cast<const bf16x8*>(Wr0 + k0);
        bf16x8 a1 = *reinterpret_cast<const bf16x8*>(Wr1 + k0);
        bf16x8 b0 = *reinterpret_cast<const bf16x8*>(Fr0 + k0);
        bf16x8 b1 = *reinterpret_cast<const bf16x8*>(Fr1 + k0);
        acc[0][0] = __builtin_amdgcn_mfma_f32_16x16x32_bf16(a0, b0, acc[0][0], 0, 0, 0);
        acc[0][1] = __builtin_amdgcn_mfma_f32_16x16x32_bf16(a0, b1, acc[0][1], 0, 0, 0);
        acc[1][0] = __builtin_amdgcn_mfma_f32_16x16x32_bf16(a1, b0, acc[1][0], 0, 0, 0);
        acc[1][1] = __builtin_amdgcn_mfma_f32_16x16x32_bf16(a1, b1, acc[1][1], 0, 0, 0);
    }

    // Epilogue: D[row=o][col=m]; col = lane&15, row = (lane>>4)*4 + i
#pragma unroll
    for (int os = 0; os < 2; ++os) {
#pragma unroll
        for (int ms = 0; ms < 2; ++ms) {
            int m  = m_base + wm * 32 + ms * 16 + l15;
            int bb = m / HW2;
            int hw = m - bb * HW2;
            int oo = o_base + wo * 32 + os * 16 + (lane >> 4) * 4;
            float* dst = out + ((unsigned)bb * NO + oo) * HW2 + hw;
            f32x4 v = acc[os][ms];
            dst[0 * HW2] = v[0];
            dst[1 * HW2] = v[1];
            dst[2 * HW2] = v[2];
            dst[3 * HW2] = v[3];
        }
    }
}

extern "C" void kernel_launch(void* const* d_in, const int* in_sizes, int n_in,
                              void* d_out, int out_size, void* d_ws, size_t ws_size,
                              hipStream_t stream) {
    const float* x1   = (const float*)d_in[0];
    const float* x3   = (const float*)d_in[1];
    const float* x5   = (const float*)d_in[2];
    const float* W    = (const float*)d_in[3];
    const int*   idx  = (const int*)d_in[4];
    const int*   offh = (const int*)d_in[5];
    const int*   offw = (const int*)d_in[6];
    float* out = (float*)d_out;

    // Workspace layout: feats bf16 [128][196][384] then Wb bf16 [768][384]
    __bf16* feats = (__bf16*)d_ws;
    __bf16* Wb    = (__bf16*)((char*)d_ws + (size_t)B * HW2 * NC * sizeof(__bf16));

    // W convert: 294912 elems
    wconv_kernel<<<(NO * NC) / 256, 256, 0, stream>>>(W, Wb);

    // Gather: 128*196*384 = 9,633,792 elems
    gather_kernel<<<(B * HW2 * NC) / 256, 256, 0, stream>>>(x1, x3, x5, idx, offh, offw, feats);

    // GEMM: grid (25088/64, 768/64) = (392, 12)
    dim3 grid(M_TOTAL / 64, NO / 64);
    gemm_kernel<<<grid, 256, 0, stream>>>(feats, Wb, out);
}

// Round 2
// 149.416 us; speedup vs baseline: 1.6017x; 1.6017x over previous
//
#include <hip/hip_runtime.h>
#include <hip/hip_bf16.h>

#define PIX 256
#define CROP 14
#define HW2 196
#define BB 128
#define CC 512
#define NC 384
#define NO 768
#define CAP 128

typedef __bf16 bf16x8 __attribute__((ext_vector_type(8)));
typedef __bf16 bf16x4 __attribute__((ext_vector_type(4)));
typedef float  f32x4  __attribute__((ext_vector_type(4)));
typedef unsigned int u32;

__global__ void wconv_kernel(const float* __restrict__ W, __bf16* __restrict__ Wb) {
    int tid = blockIdx.x * 256 + threadIdx.x;
    Wb[tid] = (__bf16)W[tid];
}

__global__ void fill_kernel(const int* __restrict__ idx, const int* __restrict__ offh,
                            const int* __restrict__ offw, int* __restrict__ cnt,
                            u32* __restrict__ bucket) {
    int tid = blockIdx.x * 256 + threadIdx.x;
    int c3 = tid / HW2;
    int hw = tid - c3 * HW2;
    int i = hw / CROP, j = hw - i * CROP;
    int p = (offh[c3] + i) * 16 + offw[c3] + j;
    int ch = idx[c3 * PIX + p];
    int bkt = (c3 >> 7) * CC + ch;
    int pos = atomicAdd(&cnt[bkt], 1);
    if (pos < CAP) bucket[bkt * CAP + pos] = ((u32)c3 << 16) | ((u32)hw << 8) | (u32)p;
}

#define LSTR 260
__global__ __launch_bounds__(256) void scatter_kernel(
        const float* __restrict__ x1, const float* __restrict__ x3,
        const float* __restrict__ x5, const int* __restrict__ cnt,
        const u32* __restrict__ bucket, __bf16* __restrict__ fT) {
    __shared__ __bf16 lds[64 * LSTR];
    int bx = blockIdx.x;
    int E = cnt[bx]; if (E > CAP) E = CAP;
    if (E == 0) return;
    int b0 = blockIdx.y * 64;
    int t = bx >> 9, ch = bx & 511;
    const float* x = (t == 0) ? x1 : (t == 1) ? x3 : x5;
    int w = threadIdx.x >> 6, lane = threadIdx.x & 63;
    for (int r = w; r < 64; r += 4) {
        f32x4 v = *(const f32x4*)(x + ((size_t)(b0 + r) * CC + ch) * PIX + lane * 4);
        bf16x4 q;
        q[0] = (__bf16)v[0]; q[1] = (__bf16)v[1]; q[2] = (__bf16)v[2]; q[3] = (__bf16)v[3];
        *(bf16x4*)&lds[r * LSTR + lane * 4] = q;
    }
    __syncthreads();
    for (int e = w; e < E; e += 4) {
        u32 pk = bucket[bx * CAP + e];
        int c3 = pk >> 16, hw = (pk >> 8) & 255, p = pk & 255;
        fT[((size_t)c3 * HW2 + hw) * BB + b0 + lane] = lds[lane * LSTR + p];
    }
}

__global__ __launch_bounds__(256) void ftrans_kernel(const __bf16* __restrict__ fT,
                                                     __bf16* __restrict__ feats) {
    __shared__ __bf16 lds[64 * 128];
    int hw = blockIdx.x;
    int c0 = blockIdx.y * 64;
    int t = threadIdx.x;
    int l16 = t & 15;
#pragma unroll
    for (int r4 = 0; r4 < 4; ++r4) {
        int cr = (t >> 4) + r4 * 16;
        bf16x8 v = *(const bf16x8*)(fT + ((size_t)(c0 + cr) * HW2 + hw) * BB + l16 * 8);
        int chunk = l16 ^ ((cr >> 3) & 7);
        *(bf16x8*)&lds[cr * 128 + chunk * 8] = v;
    }
    __syncthreads();
    int cg = t & 7;
#pragma unroll
    for (int r = 0; r < 4; ++r) {
        int b = (t >> 3) + r * 32;
        bf16x8 ov;
#pragma unroll
        for (int k = 0; k < 8; ++k) {
            int c = cg * 8 + k;
            ov[k] = lds[c * 128 + (((b >> 3) ^ cg) * 8) + (b & 7)];
        }
        *(bf16x8*)(feats + ((size_t)b * HW2 + hw) * NC + c0 + cg * 8) = ov;
    }
}

__global__ __launch_bounds__(512) void gemm_kernel(const __bf16* __restrict__ feats,
                                                   const __bf16* __restrict__ Wb,
                                                   float* __restrict__ out) {
    const int m_base = blockIdx.x * 128;
    const int o_base = blockIdx.y * 256;
    const int wave = threadIdx.x >> 6;
    const int lane = threadIdx.x & 63;
    const int wo = wave >> 1, wm = wave & 1;
    const int l15 = lane & 15;
    const int kl = (lane >> 4) * 8;

    const __bf16* A0 = Wb + (size_t)(o_base + wo * 64 + l15) * NC + kl;
    const __bf16* B0 = feats + ((size_t)m_base + wm * 64 + l15) * NC + kl;

    f32x4 acc[4][4] = {};
#pragma unroll
    for (int k0 = 0; k0 < NC; k0 += 32) {
        bf16x8 a[4], b[4];
#pragma unroll
        for (int s = 0; s < 4; ++s) {
            a[s] = *(const bf16x8*)(A0 + (size_t)s * 16 * NC + k0);
            b[s] = *(const bf16x8*)(B0 + (size_t)s * 16 * NC + k0);
        }
#pragma unroll
        for (int os = 0; os < 4; ++os)
#pragma unroll
            for (int ms = 0; ms < 4; ++ms)
                acc[os][ms] = __builtin_amdgcn_mfma_f32_16x16x32_bf16(a[os], b[ms], acc[os][ms], 0, 0, 0);
    }
#pragma unroll
    for (int os = 0; os < 4; ++os)
#pragma unroll
        for (int ms = 0; ms < 4; ++ms) {
            int m = m_base + wm * 64 + ms * 16 + l15;
            int bb = m / HW2;
            int hw = m - bb * HW2;
            int o = o_base + wo * 64 + os * 16 + (lane >> 4) * 4;
            float* dst = out + ((size_t)bb * NO + o) * HW2 + hw;
            f32x4 v = acc[os][ms];
            dst[0 * HW2] = v[0];
            dst[1 * HW2] = v[1];
            dst[2 * HW2] = v[2];
            dst[3 * HW2] = v[3];
        }
}

extern "C" void kernel_launch(void* const* d_in, const int* in_sizes, int n_in,
                              void* d_out, int out_size, void* d_ws, size_t ws_size,
                              hipStream_t stream) {
    const float* x1   = (const float*)d_in[0];
    const float* x3   = (const float*)d_in[1];
    const float* x5   = (const float*)d_in[2];
    const float* W    = (const float*)d_in[3];
    const int*   idx  = (const int*)d_in[4];
    const int*   offh = (const int*)d_in[5];
    const int*   offw = (const int*)d_in[6];
    float* out = (float*)d_out;

    char* ws = (char*)d_ws;
    __bf16* fT     = (__bf16*)(ws);              // 19,267,584 B
    __bf16* feats  = (__bf16*)(ws + 19267584);   // 19,267,584 B
    __bf16* Wb     = (__bf16*)(ws + 38535168);   // 589,824 B
    int*    cnt    = (int*)   (ws + 39124992);   // 6,144 B
    u32*    bucket = (u32*)   (ws + 39131136);   // 786,432 B

    wconv_kernel<<<(NO * NC) / 256, 256, 0, stream>>>(W, Wb);
    hipMemsetAsync(cnt, 0, 1536 * sizeof(int), stream);
    fill_kernel<<<(NC * HW2) / 256, 256, 0, stream>>>(idx, offh, offw, cnt, bucket);
    scatter_kernel<<<dim3(1536, 2), 256, 0, stream>>>(x1, x3, x5, cnt, bucket, fT);
    ftrans_kernel<<<dim3(HW2, 6), 256, 0, stream>>>(fT, feats);
    gemm_kernel<<<dim3(25088 / 128, 3), 512, 0, stream>>>(feats, Wb, out);
}